// Round 8
// baseline (411.260 us; speedup 1.0000x reference)
//
#include <hip/hip_runtime.h>
#include <hip/hip_cooperative_groups.h>

namespace cg = cooperative_groups;

// Problem constants (GATConv_17635135717523)
// N=50000 nodes, E=800000 edges, IN=256, H=8, O=32, H*O=256
#define N_NODES 50000
#define N_EDGES 800000
#define NPAD    50176   // 196*256
#define SPILL_CAP 8192
#define GEMM_TILES 782
#define GEMM_BLOCKS 782
#define BUCKET_BLOCKS 391    // fallback path: 391*512 thr * 4 edges >= E

typedef __bf16 bf16x8 __attribute__((ext_vector_type(8)));
typedef float  fx4    __attribute__((ext_vector_type(4)));
typedef unsigned short us8 __attribute__((ext_vector_type(8)));

__device__ __forceinline__ float b2f(unsigned short u) {
    return __uint_as_float(((unsigned)u) << 16);
}
__device__ __forceinline__ unsigned short f2b(float f) {
    unsigned x = __float_as_uint(f);
    return (unsigned short)((x + 0x7FFFu + ((x >> 16) & 1u)) >> 16);
}

// ============================================================== FUSED (coop)
// One cooperative kernel, 3 phases, 2 grid.sync()s. Replaces 3 dispatches:
// the per-iteration kernel sum (~145us) has trailed the benched total
// (~226us) by ~60-80us for 5 rounds -- dispatch-boundary overhead is the
// target. Phase bodies are the r7-proven ones, verbatim where possible.
__global__ __launch_bounds__(512) void fused_all(
    const float* __restrict__ feat, const float* __restrict__ W,
    const float* __restrict__ attn_l, const float* __restrict__ attn_r,
    const float* __restrict__ bias,
    const int* __restrict__ src, const int* __restrict__ dst,
    unsigned short* __restrict__ Wt,
    unsigned short* __restrict__ M2t_hi, unsigned short* __restrict__ M2t_lo,
    unsigned short* __restrict__ ft,
    float* __restrict__ el, float* __restrict__ er,
    int* __restrict__ cursor, int* __restrict__ spill_n,
    int2* __restrict__ spill, unsigned short* __restrict__ inedge,
    float* __restrict__ out, int stride) {
    __shared__ unsigned short Alds[64 * 264];        // 33792 B
    cg::grid_group grid = cg::this_grid();
    const int tid = threadIdx.x;
    const int bid = blockIdx.x;
    const int ngrid = gridDim.x;

    // ---------------- phase A: prep (barrier-free, one unit per thread)
    {
        int idx = bid * 512 + tid;
        if (idx < 8192) {
            // Wt[n][k] = bf16(W[k][n]); lanes ascend n -> coalesced reads
            int n = idx & 255, k0 = (idx >> 8) * 8;
            us8 o;
#pragma unroll
            for (int i = 0; i < 8; ++i) o[i] = f2b(W[(k0 + i) * 256 + n]);
            *reinterpret_cast<us8*>(Wt + n * 256 + k0) = o;
        } else if (idx < 12288) {
            int g2 = idx - 8192;
            int j = g2 >> 8, k = g2 & 255;
            const float* av = (j < 8) ? (attn_l + j * 32) : (attn_r + (j - 8) * 32);
            int c0 = (j & 7) * 32;
            float s = 0.f;
#pragma unroll
            for (int o = 0; o < 32; ++o) s += W[k * 256 + c0 + o] * av[o];
            unsigned short h = f2b(s);
            M2t_hi[j * 256 + k] = h;
            M2t_lo[j * 256 + k] = f2b(s - b2f(h));
        } else if (idx < 24832) {
            reinterpret_cast<int4*>(cursor)[idx - 12288] = make_int4(0, 0, 0, 0);
        } else if (idx == 24832) {
            *spill_n = 0;
        }
    }
    __threadfence();
    grid.sync();

    // ---------------- phase B: gemm tiles + edge bucketing
    // split grid: ngemm blocks get an EQUAL tile count (no straggler),
    // the rest bucket edges grid-stride (4 edges per int4 chunk).
    {
        int nbucket = ngrid / 5; if (nbucket < 1) nbucket = 1;
        int ngemm = ngrid - nbucket;
        int tpb = (GEMM_TILES + ngemm - 1) / ngemm;
        ngemm = (GEMM_TILES + tpb - 1) / tpb;
        nbucket = ngrid - ngemm;

        if (bid >= ngemm) {
            for (int t = (bid - ngemm) * 512 + tid; t < N_EDGES / 4;
                 t += nbucket * 512) {
                int4 s4 = reinterpret_cast<const int4*>(src)[t];
                int4 d4 = reinterpret_cast<const int4*>(dst)[t];
                int ss[4] = {s4.x, s4.y, s4.z, s4.w};
                int dd[4] = {d4.x, d4.y, d4.z, d4.w};
#pragma unroll
                for (int i = 0; i < 4; ++i) {
                    int idx2 = atomicAdd(&cursor[dd[i]], 1);
                    if (idx2 < stride) {
                        inedge[(size_t)dd[i] * stride + idx2] = (unsigned short)ss[i];
                    } else {
                        int sp = atomicAdd(spill_n, 1);
                        if (sp < SPILL_CAP) spill[sp] = make_int2(ss[i], dd[i]);
                    }
                }
            }
        } else {
            const int lane = tid & 63;
            const int wid  = tid >> 6;                   // 0..7
            const int quad = lane >> 4, l15 = lane & 15;
            const int nbase = wid * 32;
            const unsigned short* m2base = nullptr;
            if (wid == 1 || wid == 2) {
                int jrow = ((wid == 2) ? 8 : 0) + (l15 & 7);
                m2base = ((l15 < 8) ? M2t_hi : M2t_lo) + jrow * 256;
            }
            for (int tile = bid; tile < GEMM_TILES; tile += ngemm) {
                __syncthreads();          // Alds reuse across tile iterations
                const int mbase = tile * 64;
                fx4 acc[4][2];
                fx4 acce[4];
#pragma unroll
                for (int i = 0; i < 4; ++i) {
                    acce[i] = (fx4)0.0f;
#pragma unroll
                    for (int j = 0; j < 2; ++j) acc[i][j] = (fx4)0.0f;
                }
                // stage 64x256 tile: 8 threads per row, 128B each
                {
                    const int srow = tid >> 3, s8 = tid & 7;
                    int grow = mbase + srow;
                    grow = grow < N_NODES ? grow : N_NODES - 1;
                    const float* sp = feat + (size_t)grow * 256;
                    unsigned short* sd = &Alds[srow * 264];
#pragma unroll
                    for (int ii = 0; ii < 2; ++ii) {
                        int c8 = ii * 16 + s8 * 2;
                        float4 f0 = *reinterpret_cast<const float4*>(sp + c8 * 8);
                        float4 f1 = *reinterpret_cast<const float4*>(sp + c8 * 8 + 4);
                        float4 f2 = *reinterpret_cast<const float4*>(sp + c8 * 8 + 8);
                        float4 f3 = *reinterpret_cast<const float4*>(sp + c8 * 8 + 12);
                        us8 p0, p1;
                        p0[0] = f2b(f0.x); p0[1] = f2b(f0.y); p0[2] = f2b(f0.z); p0[3] = f2b(f0.w);
                        p0[4] = f2b(f1.x); p0[5] = f2b(f1.y); p0[6] = f2b(f1.z); p0[7] = f2b(f1.w);
                        p1[0] = f2b(f2.x); p1[1] = f2b(f2.y); p1[2] = f2b(f2.z); p1[3] = f2b(f2.w);
                        p1[4] = f2b(f3.x); p1[5] = f2b(f3.y); p1[6] = f2b(f3.z); p1[7] = f2b(f3.w);
                        *reinterpret_cast<us8*>(sd + c8 * 8) = p0;
                        *reinterpret_cast<us8*>(sd + c8 * 8 + 8) = p1;
                    }
                }
                __syncthreads();
                // K loop, barrier-free (r3/r7 form)
                for (int k0 = 0; k0 < 256; k0 += 32) {
                    const int krow = k0 + quad * 8;
                    bf16x8 a[4], b[2];
#pragma unroll
                    for (int mt = 0; mt < 4; ++mt)
                        a[mt] = *reinterpret_cast<const bf16x8*>(&Alds[(mt * 16 + l15) * 264 + krow]);
#pragma unroll
                    for (int nt = 0; nt < 2; ++nt)
                        b[nt] = *reinterpret_cast<const bf16x8*>(Wt + (nbase + nt * 16 + l15) * 256 + krow);
#pragma unroll
                    for (int mt = 0; mt < 4; ++mt)
#pragma unroll
                        for (int nt = 0; nt < 2; ++nt)
                            acc[mt][nt] = __builtin_amdgcn_mfma_f32_16x16x32_bf16(
                                a[mt], b[nt], acc[mt][nt], 0, 0, 0);
                    if (wid == 1 || wid == 2) {
                        bf16x8 bm = *reinterpret_cast<const bf16x8*>(m2base + krow);
#pragma unroll
                        for (int mt = 0; mt < 4; ++mt)
                            acce[mt] = __builtin_amdgcn_mfma_f32_16x16x32_bf16(a[mt], bm, acce[mt], 0, 0, 0);
                    }
                }
                // el/er epilogue (waves 1,2): hi(lanes 0-7)+lo(8-15) via shfl
                if (wid == 1 || wid == 2) {
                    float* dstp = (wid == 1) ? el : er;
#pragma unroll
                    for (int mt = 0; mt < 4; ++mt) {
#pragma unroll
                        for (int r = 0; r < 4; ++r) {
                            int row = mbase + mt * 16 + quad * 4 + r;
                            float c = acce[mt][r];
                            c += __shfl_xor(c, 8);
                            if (row < N_NODES && l15 < 8)
                                dstp[row * 8 + l15] = c;
                        }
                    }
                }
                __syncthreads();   // reuse Alds as bounce
                // packed epilogue: per-wave LDS bounce -> us8 ft stores
                unsigned short* bw = &Alds[wid * 512];
#pragma unroll
                for (int mt = 0; mt < 4; ++mt) {
#pragma unroll
                    for (int r = 0; r < 4; ++r) {
                        int rl = quad * 4 + r;
#pragma unroll
                        for (int nt = 0; nt < 2; ++nt)
                            bw[rl * 32 + nt * 16 + l15] = f2b(acc[mt][nt][r]);
                    }
                    {
                        int rl = lane >> 2;
                        int c8 = lane & 3;
                        us8 v = *reinterpret_cast<const us8*>(&bw[rl * 32 + c8 * 8]);
                        int grow = mbase + mt * 16 + rl;
                        if (grow < N_NODES)
                            *reinterpret_cast<us8*>(ft + (size_t)grow * 256 + nbase + c8 * 8) = v;
                    }
                }
            }
        }
    }
    __threadfence();
    grid.sync();

    // ---------------- phase C: aggregation (r7 body, grid-stride over nodes)
    {
        int wid = tid >> 6, lane = tid & 63;
        int half = lane >> 5, l = lane & 31;
        int h = l >> 2;
        int sh = half * 16;
        const us8* ft8 = reinterpret_cast<const us8*>(ft);
        for (int v = bid * 8 + wid; v < N_NODES; v += ngrid * 8) {
            int deg_t = cursor[v];
            int deg = deg_t < stride ? deg_t : stride;
            float erv = er[v * 8 + h];
            const unsigned short* ip = inedge + (size_t)v * stride;
            float a[8] = {0.f, 0.f, 0.f, 0.f, 0.f, 0.f, 0.f, 0.f};
            float s = 0.f;
            int j = 0;
            for (; j + 16 <= deg; j += 16) {
                uint4 q0 = *reinterpret_cast<const uint4*>(ip + j);
                uint4 q1 = *reinterpret_cast<const uint4*>(ip + j + 8);
                int u[8];
                u[0] = (q0.x >> sh) & 0xffff; u[1] = (q0.y >> sh) & 0xffff;
                u[2] = (q0.z >> sh) & 0xffff; u[3] = (q0.w >> sh) & 0xffff;
                u[4] = (q1.x >> sh) & 0xffff; u[5] = (q1.y >> sh) & 0xffff;
                u[6] = (q1.z >> sh) & 0xffff; u[7] = (q1.w >> sh) & 0xffff;
                us8 f[8];
#pragma unroll
                for (int t = 0; t < 8; ++t) f[t] = ft8[(size_t)u[t] * 32 + l];
                float ee[8];
#pragma unroll
                for (int t = 0; t < 8; ++t) ee[t] = el[u[t] * 8 + h];
#pragma unroll
                for (int t = 0; t < 8; ++t) {
                    float x = ee[t] + erv;
                    x = x > 0.f ? x : 0.2f * x;
                    float w = __expf(x);
                    s += w;
#pragma unroll
                    for (int i = 0; i < 8; ++i) a[i] += w * b2f(f[t][i]);
                }
            }
            for (; j + 8 <= deg; j += 8) {
                uint4 q0 = *reinterpret_cast<const uint4*>(ip + j);
                int u[4];
                u[0] = (q0.x >> sh) & 0xffff; u[1] = (q0.y >> sh) & 0xffff;
                u[2] = (q0.z >> sh) & 0xffff; u[3] = (q0.w >> sh) & 0xffff;
                us8 f[4];
#pragma unroll
                for (int t = 0; t < 4; ++t) f[t] = ft8[(size_t)u[t] * 32 + l];
#pragma unroll
                for (int t = 0; t < 4; ++t) {
                    float x = el[u[t] * 8 + h] + erv;
                    x = x > 0.f ? x : 0.2f * x;
                    float w = __expf(x);
                    s += w;
#pragma unroll
                    for (int i = 0; i < 8; ++i) a[i] += w * b2f(f[t][i]);
                }
            }
            for (; j + 2 <= deg; j += 2) {
                int u = ip[j + half];
                us8 f = ft8[(size_t)u * 32 + l];
                float x = el[u * 8 + h] + erv;
                x = x > 0.f ? x : 0.2f * x;
                float w = __expf(x);
                s += w;
#pragma unroll
                for (int i = 0; i < 8; ++i) a[i] += w * b2f(f[i]);
            }
            if (j < deg && half == 0) {
                int u = ip[j];
                us8 f = ft8[(size_t)u * 32 + l];
                float x = el[u * 8 + h] + erv;
                x = x > 0.f ? x : 0.2f * x;
                float w = __expf(x);
                s += w;
#pragma unroll
                for (int i = 0; i < 8; ++i) a[i] += w * b2f(f[i]);
            }
            if (deg_t > stride) {
                int sn = *spill_n;
                if (sn > SPILL_CAP) sn = SPILL_CAP;
                for (int t = 0; t < sn; ++t) {
                    int2 e = spill[t];
                    if (e.y == v && half == 0) {
                        int u = e.x;
                        us8 f = ft8[(size_t)u * 32 + l];
                        float x = el[u * 8 + h] + erv;
                        x = x > 0.f ? x : 0.2f * x;
                        float w = __expf(x);
                        s += w;
#pragma unroll
                        for (int i = 0; i < 8; ++i) a[i] += w * b2f(f[i]);
                    }
                }
            }
#pragma unroll
            for (int i = 0; i < 8; ++i) a[i] += __shfl_xor(a[i], 32);
            s += __shfl_xor(s, 32);
            float inv = deg_t > 0 ? 1.0f / s : 0.f;
            int fi = l * 2 + half;
            float4 bb = reinterpret_cast<const float4*>(bias)[fi];
            int base = half * 4;
            float4 o;
            o.x = a[base + 0] * inv + bb.x;
            o.y = a[base + 1] * inv + bb.y;
            o.z = a[base + 2] * inv + bb.z;
            o.w = a[base + 3] * inv + bb.w;
            reinterpret_cast<float4*>(out)[(size_t)v * 64 + fi] = o;
        }
    }
}

// ============================================================== FALLBACK
// Exact round-7 3-kernel pipeline (proven 226us) -- used if the cooperative
// launch is unavailable (e.g. unsupported under graph capture).

__global__ __launch_bounds__(256) void prep_w(
    const float* __restrict__ W,
    const float* __restrict__ attn_l, const float* __restrict__ attn_r,
    unsigned short* __restrict__ Wt,
    unsigned short* __restrict__ M2t_hi, unsigned short* __restrict__ M2t_lo,
    int* __restrict__ cursor, int* __restrict__ spill_n) {
    __shared__ float T[64 * 65];
    int b = blockIdx.x, t = threadIdx.x;
    if (b < 16) {
        int bi = b >> 2, bj = b & 3;
        int r = t >> 2, cq = t & 3;
        const float* wp = W + (size_t)(bi * 64 + r) * 256 + bj * 64 + cq * 16;
#pragma unroll
        for (int i = 0; i < 16; ++i) T[r * 65 + cq * 16 + i] = wp[i];
        __syncthreads();
        int n = t >> 2, ks = (t & 3) * 16;
        us8 o0, o1;
#pragma unroll
        for (int i = 0; i < 8; ++i) o0[i] = f2b(T[(ks + i) * 65 + n]);
#pragma unroll
        for (int i = 0; i < 8; ++i) o1[i] = f2b(T[(ks + 8 + i) * 65 + n]);
        unsigned short* op = Wt + (size_t)(bj * 64 + n) * 256 + bi * 64 + ks;
        *reinterpret_cast<us8*>(op) = o0;
        *reinterpret_cast<us8*>(op + 8) = o1;
    } else if (b < 32) {
        int j = b - 16;
        const float* av = (j < 8) ? (attn_l + j * 32) : (attn_r + (j - 8) * 32);
        int c0 = (j & 7) * 32;
        float s = 0.f;
#pragma unroll
        for (int o = 0; o < 32; ++o) s += W[t * 256 + c0 + o] * av[o];
        unsigned short h = f2b(s);
        M2t_hi[j * 256 + t] = h;
        M2t_lo[j * 256 + t] = f2b(s - b2f(h));
    } else {
        cursor[(b - 32) * 256 + t] = 0;
        if (b == 32 && t == 0) *spill_n = 0;
    }
}

__global__ __launch_bounds__(512) void gemm_bucket(
    const float* __restrict__ feat,
    const unsigned short* __restrict__ Wt,
    const unsigned short* __restrict__ M2t_hi,
    const unsigned short* __restrict__ M2t_lo,
    unsigned short* __restrict__ ft,
    float* __restrict__ el, float* __restrict__ er,
    const int* __restrict__ src, const int* __restrict__ dst,
    int* __restrict__ cursor, unsigned short* __restrict__ inedge,
    int* __restrict__ spill_n, int2* __restrict__ spill, int stride) {
    __shared__ unsigned short Alds[64 * 264];
    const int tid = threadIdx.x;
    if (blockIdx.x >= GEMM_BLOCKS) {
        int t = (blockIdx.x - GEMM_BLOCKS) * 512 + tid;
        if (t < N_EDGES / 4) {
            int4 s4 = reinterpret_cast<const int4*>(src)[t];
            int4 d4 = reinterpret_cast<const int4*>(dst)[t];
            int ss[4] = {s4.x, s4.y, s4.z, s4.w};
            int dd[4] = {d4.x, d4.y, d4.z, d4.w};
#pragma unroll
            for (int i = 0; i < 4; ++i) {
                int idx = atomicAdd(&cursor[dd[i]], 1);
                if (idx < stride) {
                    inedge[(size_t)dd[i] * stride + idx] = (unsigned short)ss[i];
                } else {
                    int sp = atomicAdd(spill_n, 1);
                    if (sp < SPILL_CAP) spill[sp] = make_int2(ss[i], dd[i]);
                }
            }
        }
        return;
    }
    const int lane = tid & 63;
    const int wid  = tid >> 6;
    const int quad = lane >> 4, l15 = lane & 15;
    const int mbase = blockIdx.x * 64;
    const int nbase = wid * 32;
    const unsigned short* m2base = nullptr;
    if (wid == 1 || wid == 2) {
        int jrow = ((wid == 2) ? 8 : 0) + (l15 & 7);
        m2base = ((l15 < 8) ? M2t_hi : M2t_lo) + jrow * 256;
    }
    fx4 acc[4][2];
    fx4 acce[4];
#pragma unroll
    for (int i = 0; i < 4; ++i) {
        acce[i] = (fx4)0.0f;
#pragma unroll
        for (int j = 0; j < 2; ++j) acc[i][j] = (fx4)0.0f;
    }
    {
        const int srow = tid >> 3, s8 = tid & 7;
        int grow = mbase + srow;
        grow = grow < N_NODES ? grow : N_NODES - 1;
        const float* sp = feat + (size_t)grow * 256;
        unsigned short* sd = &Alds[srow * 264];
#pragma unroll
        for (int ii = 0; ii < 2; ++ii) {
            int c8 = ii * 16 + s8 * 2;
            float4 f0 = *reinterpret_cast<const float4*>(sp + c8 * 8);
            float4 f1 = *reinterpret_cast<const float4*>(sp + c8 * 8 + 4);
            float4 f2 = *reinterpret_cast<const float4*>(sp + c8 * 8 + 8);
            float4 f3 = *reinterpret_cast<const float4*>(sp + c8 * 8 + 12);
            us8 p0, p1;
            p0[0] = f2b(f0.x); p0[1] = f2b(f0.y); p0[2] = f2b(f0.z); p0[3] = f2b(f0.w);
            p0[4] = f2b(f1.x); p0[5] = f2b(f1.y); p0[6] = f2b(f1.z); p0[7] = f2b(f1.w);
            p1[0] = f2b(f2.x); p1[1] = f2b(f2.y); p1[2] = f2b(f2.z); p1[3] = f2b(f2.w);
            p1[4] = f2b(f3.x); p1[5] = f2b(f3.y); p1[6] = f2b(f3.z); p1[7] = f2b(f3.w);
            *reinterpret_cast<us8*>(sd + c8 * 8) = p0;
            *reinterpret_cast<us8*>(sd + c8 * 8 + 8) = p1;
        }
    }
    __syncthreads();
    for (int k0 = 0; k0 < 256; k0 += 32) {
        const int krow = k0 + quad * 8;
        bf16x8 a[4], b[2];
#pragma unroll
        for (int mt = 0; mt < 4; ++mt)
            a[mt] = *reinterpret_cast<const bf16x8*>(&Alds[(mt * 16 + l15) * 264 + krow]);
#pragma unroll
        for (int nt = 0; nt < 2; ++nt)
            b[nt] = *reinterpret_cast<const bf16x8*>(Wt + (nbase + nt * 16 + l15) * 256 + krow);
#pragma unroll
        for (int mt = 0; mt < 4; ++mt)
#pragma unroll
            for (int nt = 0; nt < 2; ++nt)
                acc[mt][nt] = __builtin_amdgcn_mfma_f32_16x16x32_bf16(
                    a[mt], b[nt], acc[mt][nt], 0, 0, 0);
        if (wid == 1 || wid == 2) {
            bf16x8 bm = *reinterpret_cast<const bf16x8*>(m2base + krow);
#pragma unroll
            for (int mt = 0; mt < 4; ++mt)
                acce[mt] = __builtin_amdgcn_mfma_f32_16x16x32_bf16(a[mt], bm, acce[mt], 0, 0, 0);
        }
    }
    if (wid == 1 || wid == 2) {
        float* dstp = (wid == 1) ? el : er;
#pragma unroll
        for (int mt = 0; mt < 4; ++mt) {
#pragma unroll
            for (int r = 0; r < 4; ++r) {
                int row = mbase + mt * 16 + quad * 4 + r;
                float c = acce[mt][r];
                c += __shfl_xor(c, 8);
                if (row < N_NODES && l15 < 8)
                    dstp[row * 8 + l15] = c;
            }
        }
    }
    __syncthreads();
    unsigned short* bw = &Alds[wid * 512];
#pragma unroll
    for (int mt = 0; mt < 4; ++mt) {
#pragma unroll
        for (int r = 0; r < 4; ++r) {
            int rl = quad * 4 + r;
#pragma unroll
            for (int nt = 0; nt < 2; ++nt)
                bw[rl * 32 + nt * 16 + l15] = f2b(acc[mt][nt][r]);
        }
        {
            int rl = lane >> 2;
            int c8 = lane & 3;
            us8 v = *reinterpret_cast<const us8*>(&bw[rl * 32 + c8 * 8]);
            int grow = mbase + mt * 16 + rl;
            if (grow < N_NODES)
                *reinterpret_cast<us8*>(ft + (size_t)grow * 256 + nbase + c8 * 8) = v;
        }
    }
}

__global__ __launch_bounds__(256) void aggregate(
    const unsigned short* __restrict__ ft,
    const float* __restrict__ el, const float* __restrict__ er,
    const int* __restrict__ cursor,
    const unsigned short* __restrict__ inedge,
    const int* __restrict__ spill_n, const int2* __restrict__ spill,
    const float* __restrict__ bias,
    float* __restrict__ out, int stride) {
    int wid = threadIdx.x >> 6, lane = threadIdx.x & 63;
    int v = blockIdx.x * 4 + wid;
    int deg_t = cursor[v];
    int deg = deg_t < stride ? deg_t : stride;
    int half = lane >> 5, l = lane & 31;
    int h = l >> 2;
    int sh = half * 16;
    float erv = er[v * 8 + h];
    const unsigned short* ip = inedge + (size_t)v * stride;
    const us8* ft8 = reinterpret_cast<const us8*>(ft);
    float a[8] = {0.f, 0.f, 0.f, 0.f, 0.f, 0.f, 0.f, 0.f};
    float s = 0.f;
    int j = 0;
    for (; j + 16 <= deg; j += 16) {
        uint4 q0 = *reinterpret_cast<const uint4*>(ip + j);
        uint4 q1 = *reinterpret_cast<const uint4*>(ip + j + 8);
        int u[8];
        u[0] = (q0.x >> sh) & 0xffff; u[1] = (q0.y >> sh) & 0xffff;
        u[2] = (q0.z >> sh) & 0xffff; u[3] = (q0.w >> sh) & 0xffff;
        u[4] = (q1.x >> sh) & 0xffff; u[5] = (q1.y >> sh) & 0xffff;
        u[6] = (q1.z >> sh) & 0xffff; u[7] = (q1.w >> sh) & 0xffff;
        us8 f[8];
#pragma unroll
        for (int t = 0; t < 8; ++t) f[t] = ft8[(size_t)u[t] * 32 + l];
        float ee[8];
#pragma unroll
        for (int t = 0; t < 8; ++t) ee[t] = el[u[t] * 8 + h];
#pragma unroll
        for (int t = 0; t < 8; ++t) {
            float x = ee[t] + erv;
            x = x > 0.f ? x : 0.2f * x;
            float w = __expf(x);
            s += w;
#pragma unroll
            for (int i = 0; i < 8; ++i) a[i] += w * b2f(f[t][i]);
        }
    }
    for (; j + 8 <= deg; j += 8) {
        uint4 q0 = *reinterpret_cast<const uint4*>(ip + j);
        int u[4];
        u[0] = (q0.x >> sh) & 0xffff; u[1] = (q0.y >> sh) & 0xffff;
        u[2] = (q0.z >> sh) & 0xffff; u[3] = (q0.w >> sh) & 0xffff;
        us8 f[4];
#pragma unroll
        for (int t = 0; t < 4; ++t) f[t] = ft8[(size_t)u[t] * 32 + l];
#pragma unroll
        for (int t = 0; t < 4; ++t) {
            float x = el[u[t] * 8 + h] + erv;
            x = x > 0.f ? x : 0.2f * x;
            float w = __expf(x);
            s += w;
#pragma unroll
            for (int i = 0; i < 8; ++i) a[i] += w * b2f(f[t][i]);
        }
    }
    for (; j + 2 <= deg; j += 2) {
        int u = ip[j + half];
        us8 f = ft8[(size_t)u * 32 + l];
        float x = el[u * 8 + h] + erv;
        x = x > 0.f ? x : 0.2f * x;
        float w = __expf(x);
        s += w;
#pragma unroll
        for (int i = 0; i < 8; ++i) a[i] += w * b2f(f[i]);
    }
    if (j < deg && half == 0) {
        int u = ip[j];
        us8 f = ft8[(size_t)u * 32 + l];
        float x = el[u * 8 + h] + erv;
        x = x > 0.f ? x : 0.2f * x;
        float w = __expf(x);
        s += w;
#pragma unroll
        for (int i = 0; i < 8; ++i) a[i] += w * b2f(f[i]);
    }
    if (deg_t > stride) {
        int sn = *spill_n;
        if (sn > SPILL_CAP) sn = SPILL_CAP;
        for (int t = 0; t < sn; ++t) {
            int2 e = spill[t];
            if (e.y == v && half == 0) {
                int u = e.x;
                us8 f = ft8[(size_t)u * 32 + l];
                float x = el[u * 8 + h] + erv;
                x = x > 0.f ? x : 0.2f * x;
                float w = __expf(x);
                s += w;
#pragma unroll
                for (int i = 0; i < 8; ++i) a[i] += w * b2f(f[i]);
            }
        }
    }
#pragma unroll
    for (int i = 0; i < 8; ++i) a[i] += __shfl_xor(a[i], 32);
    s += __shfl_xor(s, 32);
    float inv = deg_t > 0 ? 1.0f / s : 0.f;
    int fi = l * 2 + half;
    float4 bb = reinterpret_cast<const float4*>(bias)[fi];
    int base = half * 4;
    float4 o;
    o.x = a[base + 0] * inv + bb.x;
    o.y = a[base + 1] * inv + bb.y;
    o.z = a[base + 2] * inv + bb.z;
    o.w = a[base + 3] * inv + bb.w;
    reinterpret_cast<float4*>(out)[(size_t)v * 64 + fi] = o;
}

// ------------------------------------------------------- launch
extern "C" void kernel_launch(void* const* d_in, const int* in_sizes, int n_in,
                              void* d_out, int out_size, void* d_ws, size_t ws_size,
                              hipStream_t stream) {
    const float* feat   = (const float*)d_in[0];
    const float* W      = (const float*)d_in[1];
    const float* attn_l = (const float*)d_in[2];
    const float* attn_r = (const float*)d_in[3];
    const float* bias   = (const float*)d_in[4];
    const int* src = (const int*)d_in[5];
    const int* dst = (const int*)d_in[6];
    float* out = (float*)d_out;

    char* ws = (char*)d_ws;
    unsigned short* Wt     = (unsigned short*)(ws + 0);          //    131,072
    unsigned short* M2t_hi = (unsigned short*)(ws + 131072);     //      8,192
    unsigned short* M2t_lo = (unsigned short*)(ws + 139264);     //      8,192
    unsigned short* ft     = (unsigned short*)(ws + 147456);     // 25,600,000
    float* el              = (float*)(ws + 25747456);            //  1,600,000
    float* er              = (float*)(ws + 27347456);            //  1,600,000
    int* cursor            = (int*)(ws + 28947456);              //    200,704
    int* spill_n           = (int*)(ws + 29148160);              //         64
    int2* spill            = (int2*)(ws + 29148224);             //     65,536
    unsigned short* inedge = (unsigned short*)(ws + 29213760);   // stride*2*NPAD

    size_t avail = ws_size > 29213760ull ? ws_size - 29213760ull : 0;
    int stride = (int)(avail / (2ull * NPAD));
    stride &= ~7;
    if (stride > 64) stride = 64;
    if (stride < 8) stride = 8;

    // cooperative grid size: all blocks must be co-resident.
    static int coop_grid = -2;                      // -2 uninit, -1 disabled
    if (coop_grid == -2) {
        int bpc = 0;
        hipError_t qe = hipOccupancyMaxActiveBlocksPerMultiprocessor(
            &bpc, fused_all, 512, 0);
        coop_grid = (qe == hipSuccess && bpc >= 1) ? bpc * 256 : -1;
        if (coop_grid > 1024) coop_grid = 1024;
        if (coop_grid >= 0 && coop_grid < 256) coop_grid = -1;
    }

    bool launched = false;
    if (coop_grid > 0) {
        void* kargs[] = {
            (void*)&feat, (void*)&W, (void*)&attn_l, (void*)&attn_r,
            (void*)&bias, (void*)&src, (void*)&dst,
            (void*)&Wt, (void*)&M2t_hi, (void*)&M2t_lo,
            (void*)&ft, (void*)&el, (void*)&er,
            (void*)&cursor, (void*)&spill_n, (void*)&spill, (void*)&inedge,
            (void*)&out, (void*)&stride,
        };
        hipError_t le = hipLaunchCooperativeKernel(
            reinterpret_cast<void*>(fused_all), dim3(coop_grid), dim3(512),
            kargs, 0, stream);
        if (le == hipSuccess) {
            launched = true;
        } else {
            (void)hipGetLastError();   // clear; fall back permanently
            coop_grid = -1;
        }
    }

    if (!launched) {
        // round-7 proven 3-dispatch pipeline
        prep_w<<<228, 256, 0, stream>>>(W, attn_l, attn_r, Wt, M2t_hi, M2t_lo,
                                        cursor, spill_n);
        gemm_bucket<<<GEMM_BLOCKS + BUCKET_BLOCKS, 512, 0, stream>>>(
            feat, Wt, M2t_hi, M2t_lo, ft, el, er,
            src, dst, cursor, inedge, spill_n, spill, stride);
        aggregate<<<12500, 256, 0, stream>>>(ft, el, er, cursor, inedge,
                                             spill_n, spill, bias, out, stride);
    }
}

// Round 9
// 240.863 us; speedup vs baseline: 1.7074x; 1.7074x over previous
//
#include <hip/hip_runtime.h>

// Problem constants (GATConv_17635135717523)
// N=50000 nodes, E=800000 edges, IN=256, H=8, O=32, H*O=256
#define N_NODES 50000
#define N_EDGES 800000
#define NPAD    50176   // 196*256
#define SPILL_CAP 8192
#define GEMM_BLOCKS 782
#define BUCKET_BLOCKS 391    // 391*512 threads * 4 edges = 800768 >= E

typedef __bf16 bf16x8 __attribute__((ext_vector_type(8)));
typedef float  fx4    __attribute__((ext_vector_type(4)));
typedef unsigned short us8 __attribute__((ext_vector_type(8)));

__device__ __forceinline__ float b2f(unsigned short u) {
    return __uint_as_float(((unsigned)u) << 16);
}
__device__ __forceinline__ unsigned short f2b(float f) {
    unsigned x = __float_as_uint(f);
    return (unsigned short)((x + 0x7FFFu + ((x >> 16) & 1u)) >> 16);
}

// ------------------------------------------------------- prep
// blocks 0..15: coalesced W transpose via LDS 64x64 tiles -> Wt bf16 [n][k]
// blocks 16..211: zero cursor; block 16 also zeroes spill_n
// (M2/el/er machinery removed: aggregate now derives attention logits
//  on the fly from the ft rows it already gathers.)
__global__ __launch_bounds__(256) void prep_w(
    const float* __restrict__ W,
    unsigned short* __restrict__ Wt,
    int* __restrict__ cursor, int* __restrict__ spill_n) {
    __shared__ float T[64 * 65];
    int b = blockIdx.x, t = threadIdx.x;
    if (b < 16) {
        int bi = b >> 2, bj = b & 3;          // k-tile, n-tile
        int r = t >> 2, cq = t & 3;           // k-local row, col quarter
        const float* wp = W + (size_t)(bi * 64 + r) * 256 + bj * 64 + cq * 16;
#pragma unroll
        for (int i = 0; i < 16; ++i) T[r * 65 + cq * 16 + i] = wp[i];
        __syncthreads();
        int n = t >> 2, ks = (t & 3) * 16;    // n-local, k-chunk
        us8 o0, o1;
#pragma unroll
        for (int i = 0; i < 8; ++i) o0[i] = f2b(T[(ks + i) * 65 + n]);
#pragma unroll
        for (int i = 0; i < 8; ++i) o1[i] = f2b(T[(ks + 8 + i) * 65 + n]);
        unsigned short* op = Wt + (size_t)(bj * 64 + n) * 256 + bi * 64 + ks;
        *reinterpret_cast<us8*>(op) = o0;
        *reinterpret_cast<us8*>(op + 8) = o1;
    } else {
        cursor[(b - 16) * 256 + t] = 0;
        if (b == 16 && t == 0) *spill_n = 0;
    }
}

// ------------------------------------------------------- fused GEMM + bucket
// Heterogeneous grid, 512 threads/block.
//   blocks [0, GEMM_BLOCKS): ft = bf16(feat @ W) -- round-3/7 proven
//     structure (264-stride LDS tile, in-loop B loads, 2 barriers, per-wave
//     1KB bounce epilogue), now with UNIFORM waves: the M2/el/er side path
//     is gone entirely (aggregate derives logits from ft).
//   blocks [GEMM_BLOCKS, +BUCKET_BLOCKS): bucketing at 4 edges/thread
//     (int4 loads): 4 independent atomic chains per thread under the
//     LDS-inherited 4-blocks/CU cap.
__global__ __launch_bounds__(512) void gemm_bucket(
    const float* __restrict__ feat,
    const unsigned short* __restrict__ Wt,
    unsigned short* __restrict__ ft,
    const int* __restrict__ src, const int* __restrict__ dst,
    int* __restrict__ cursor, unsigned short* __restrict__ inedge,
    int* __restrict__ spill_n, int2* __restrict__ spill, int stride) {
    __shared__ unsigned short Alds[64 * 264];        // 33792 B (also bounce)
    const int tid = threadIdx.x;

    if (blockIdx.x >= GEMM_BLOCKS) {
        // ---------------- bucket part: 4 edges per thread ----------------
        int t = (blockIdx.x - GEMM_BLOCKS) * 512 + tid;
        if (t < N_EDGES / 4) {
            int4 s4 = reinterpret_cast<const int4*>(src)[t];
            int4 d4 = reinterpret_cast<const int4*>(dst)[t];
            int ss[4] = {s4.x, s4.y, s4.z, s4.w};
            int dd[4] = {d4.x, d4.y, d4.z, d4.w};
#pragma unroll
            for (int i = 0; i < 4; ++i) {
                int idx = atomicAdd(&cursor[dd[i]], 1);
                if (idx < stride) {
                    inedge[(size_t)dd[i] * stride + idx] = (unsigned short)ss[i];
                } else {
                    int sp = atomicAdd(spill_n, 1);
                    if (sp < SPILL_CAP) spill[sp] = make_int2(ss[i], dd[i]);
                }
            }
        }
        return;
    }

    // ---------------- gemm part ----------------
    const int lane = tid & 63;
    const int wid  = tid >> 6;                       // 0..7
    const int quad = lane >> 4, l15 = lane & 15;
    const int mbase = blockIdx.x * 64;
    const int nbase = wid * 32;

    fx4 acc[4][2];
#pragma unroll
    for (int i = 0; i < 4; ++i)
#pragma unroll
        for (int j = 0; j < 2; ++j) acc[i][j] = (fx4)0.0f;

    // ---- stage whole 64x256 tile: 8 threads per row, 128B each
    {
        const int srow = tid >> 3, s8 = tid & 7;
        int grow = mbase + srow;
        grow = grow < N_NODES ? grow : N_NODES - 1;
        const float* sp = feat + (size_t)grow * 256;
        unsigned short* sd = &Alds[srow * 264];
#pragma unroll
        for (int ii = 0; ii < 2; ++ii) {
            int c8 = ii * 16 + s8 * 2;               // 8-float group index
            float4 f0 = *reinterpret_cast<const float4*>(sp + c8 * 8);
            float4 f1 = *reinterpret_cast<const float4*>(sp + c8 * 8 + 4);
            float4 f2 = *reinterpret_cast<const float4*>(sp + c8 * 8 + 8);
            float4 f3 = *reinterpret_cast<const float4*>(sp + c8 * 8 + 12);
            us8 p0, p1;
            p0[0] = f2b(f0.x); p0[1] = f2b(f0.y); p0[2] = f2b(f0.z); p0[3] = f2b(f0.w);
            p0[4] = f2b(f1.x); p0[5] = f2b(f1.y); p0[6] = f2b(f1.z); p0[7] = f2b(f1.w);
            p1[0] = f2b(f2.x); p1[1] = f2b(f2.y); p1[2] = f2b(f2.z); p1[3] = f2b(f2.w);
            p1[4] = f2b(f3.x); p1[5] = f2b(f3.y); p1[6] = f2b(f3.z); p1[7] = f2b(f3.w);
            *reinterpret_cast<us8*>(sd + c8 * 8) = p0;
            *reinterpret_cast<us8*>(sd + c8 * 8 + 8) = p1;
        }
    }
    __syncthreads();

    // ---- K loop, barrier-free (r3/r7 form: B loaded in-loop)
    for (int k0 = 0; k0 < 256; k0 += 32) {
        const int krow = k0 + quad * 8;
        bf16x8 a[4], b[2];
#pragma unroll
        for (int mt = 0; mt < 4; ++mt)
            a[mt] = *reinterpret_cast<const bf16x8*>(&Alds[(mt * 16 + l15) * 264 + krow]);
#pragma unroll
        for (int nt = 0; nt < 2; ++nt)
            b[nt] = *reinterpret_cast<const bf16x8*>(Wt + (nbase + nt * 16 + l15) * 256 + krow);
#pragma unroll
        for (int mt = 0; mt < 4; ++mt)
#pragma unroll
            for (int nt = 0; nt < 2; ++nt)
                acc[mt][nt] = __builtin_amdgcn_mfma_f32_16x16x32_bf16(
                    a[mt], b[nt], acc[mt][nt], 0, 0, 0);
    }
    __syncthreads();   // all waves done reading Alds -> reuse as bounce

    // ---- packed epilogue: per-wave LDS bounce -> us8 (16B) ft stores
    // C/D layout: col = lane&15, row = (lane>>4)*4 + reg  [verified m89/m91]
    unsigned short* bw = &Alds[wid * 512];   // 1KB per wave, wave-private
#pragma unroll
    for (int mt = 0; mt < 4; ++mt) {
#pragma unroll
        for (int r = 0; r < 4; ++r) {
            int rl = quad * 4 + r;
#pragma unroll
            for (int nt = 0; nt < 2; ++nt)
                bw[rl * 32 + nt * 16 + l15] = f2b(acc[mt][nt][r]);
        }
        // wave-internal ds ordering; compiler inserts lgkmcnt wait
        {
            int rl = lane >> 2;              // 0..15
            int c8 = lane & 3;               // 0..3 (8-short chunks)
            us8 v = *reinterpret_cast<const us8*>(&bw[rl * 32 + c8 * 8]);
            int grow = mbase + mt * 16 + rl;
            if (grow < N_NODES)
                *reinterpret_cast<us8*>(ft + (size_t)grow * 256 + nbase + c8 * 8) = v;
        }
    }
}

// ------------------------------------------------------- aggregation
// One wave per dst node, 4 waves per block, HALF-WAVE per edge (32 lanes =
// full 512B ft row at 16B/lane). 16-edge batches via two uint4 index loads
// (8 ft gathers in flight per lane).
// NEW: attention logits computed ON THE FLY from the ft rows already in
// registers -- no el/er arrays, no per-edge scalar gather. Lane l holds
// ft[u, l*8..l*8+7]; the 4 lanes of head h=l>>2 hold u's full head row, so
// el(u,h) = dot(f, attn_l slice) reduced with shfl_xor(1),(2). er(v,h) is
// computed once per node from v's own row the same way.
__global__ __launch_bounds__(256) void aggregate(
    const unsigned short* __restrict__ ft,
    const float* __restrict__ attn_l, const float* __restrict__ attn_r,
    const int* __restrict__ cursor,
    const unsigned short* __restrict__ inedge,
    const int* __restrict__ spill_n, const int2* __restrict__ spill,
    const float* __restrict__ bias,
    float* __restrict__ out, int stride) {
    int wid = threadIdx.x >> 6, lane = threadIdx.x & 63;
    int v = blockIdx.x * 4 + wid;          // grid exact: v < N always
    int deg_t = cursor[v];
    int deg = deg_t < stride ? deg_t : stride;   // bucketed edges
    int half = lane >> 5, l = lane & 31;
    int h = l >> 2;                         // head of elems [l*8, l*8+8)
    int sh = half * 16;
    const unsigned short* ip = inedge + (size_t)v * stride;
    const us8* ft8 = reinterpret_cast<const us8*>(ft);

    // per-lane attn_l slice: elements h*32 + (l&3)*8 + i  (32B aligned)
    float al8[8];
    {
        const float4* alp = reinterpret_cast<const float4*>(
            attn_l + h * 32 + (l & 3) * 8);
        float4 a0 = alp[0], a1 = alp[1];
        al8[0] = a0.x; al8[1] = a0.y; al8[2] = a0.z; al8[3] = a0.w;
        al8[4] = a1.x; al8[5] = a1.y; al8[6] = a1.z; al8[7] = a1.w;
    }
    // er(v,h): dot of v's own row with attn_r slice, 4-lane reduce
    float erv;
    {
        const float4* arp = reinterpret_cast<const float4*>(
            attn_r + h * 32 + (l & 3) * 8);
        float4 r0 = arp[0], r1 = arp[1];
        us8 fv = ft8[(size_t)v * 32 + l];
        float d = b2f(fv[0]) * r0.x + b2f(fv[1]) * r0.y +
                  b2f(fv[2]) * r0.z + b2f(fv[3]) * r0.w +
                  b2f(fv[4]) * r1.x + b2f(fv[5]) * r1.y +
                  b2f(fv[6]) * r1.z + b2f(fv[7]) * r1.w;
        d += __shfl_xor(d, 1);
        d += __shfl_xor(d, 2);
        erv = d;
    }

    float a[8] = {0.f, 0.f, 0.f, 0.f, 0.f, 0.f, 0.f, 0.f};
    float s = 0.f;
    int j = 0;
    for (; j + 16 <= deg; j += 16) {        // 8 pairs = 16 edges per iter
        uint4 q0 = *reinterpret_cast<const uint4*>(ip + j);
        uint4 q1 = *reinterpret_cast<const uint4*>(ip + j + 8);
        int u[8];
        u[0] = (q0.x >> sh) & 0xffff; u[1] = (q0.y >> sh) & 0xffff;
        u[2] = (q0.z >> sh) & 0xffff; u[3] = (q0.w >> sh) & 0xffff;
        u[4] = (q1.x >> sh) & 0xffff; u[5] = (q1.y >> sh) & 0xffff;
        u[6] = (q1.z >> sh) & 0xffff; u[7] = (q1.w >> sh) & 0xffff;
        us8 f[8];
#pragma unroll
        for (int t = 0; t < 8; ++t) f[t] = ft8[(size_t)u[t] * 32 + l];
#pragma unroll
        for (int t = 0; t < 8; ++t) {
            float fl[8];
#pragma unroll
            for (int i = 0; i < 8; ++i) fl[i] = b2f(f[t][i]);
            float d = fl[0] * al8[0] + fl[1] * al8[1] + fl[2] * al8[2] +
                      fl[3] * al8[3] + fl[4] * al8[4] + fl[5] * al8[5] +
                      fl[6] * al8[6] + fl[7] * al8[7];
            d += __shfl_xor(d, 1);
            d += __shfl_xor(d, 2);
            float x = d + erv;
            x = x > 0.f ? x : 0.2f * x;
            float w = __expf(x);
            s += w;
#pragma unroll
            for (int i = 0; i < 8; ++i) a[i] += w * fl[i];
        }
    }
    for (; j + 2 <= deg; j += 2) {          // pair tail
        int u = ip[j + half];
        us8 f = ft8[(size_t)u * 32 + l];
        float fl[8];
#pragma unroll
        for (int i = 0; i < 8; ++i) fl[i] = b2f(f[i]);
        float d = fl[0] * al8[0] + fl[1] * al8[1] + fl[2] * al8[2] +
                  fl[3] * al8[3] + fl[4] * al8[4] + fl[5] * al8[5] +
                  fl[6] * al8[6] + fl[7] * al8[7];
        d += __shfl_xor(d, 1);
        d += __shfl_xor(d, 2);
        float x = d + erv;
        x = x > 0.f ? x : 0.2f * x;
        float w = __expf(x);
        s += w;
#pragma unroll
        for (int i = 0; i < 8; ++i) a[i] += w * fl[i];
    }
    if (j < deg && half == 0) {             // odd edge: half 0 only
        int u = ip[j];
        us8 f = ft8[(size_t)u * 32 + l];
        float fl[8];
#pragma unroll
        for (int i = 0; i < 8; ++i) fl[i] = b2f(f[i]);
        float d = fl[0] * al8[0] + fl[1] * al8[1] + fl[2] * al8[2] +
                  fl[3] * al8[3] + fl[4] * al8[4] + fl[5] * al8[5] +
                  fl[6] * al8[6] + fl[7] * al8[7];
        d += __shfl_xor(d, 1);
        d += __shfl_xor(d, 2);
        float x = d + erv;
        x = x > 0.f ? x : 0.2f * x;
        float w = __expf(x);
        s += w;
#pragma unroll
        for (int i = 0; i < 8; ++i) a[i] += w * fl[i];
    }
    // spilled edges (expected never taken; correctness net for deg>stride)
    if (deg_t > stride) {
        int sn = *spill_n;
        if (sn > SPILL_CAP) sn = SPILL_CAP;
        for (int t = 0; t < sn; ++t) {
            int2 e = spill[t];
            if (e.y == v && half == 0) {
                int u = e.x;
                us8 f = ft8[(size_t)u * 32 + l];
                float fl[8];
#pragma unroll
                for (int i = 0; i < 8; ++i) fl[i] = b2f(f[i]);
                float d = fl[0] * al8[0] + fl[1] * al8[1] + fl[2] * al8[2] +
                          fl[3] * al8[3] + fl[4] * al8[4] + fl[5] * al8[5] +
                          fl[6] * al8[6] + fl[7] * al8[7];
                d += __shfl_xor(d, 1);
                d += __shfl_xor(d, 2);
                float x = d + erv;
                x = x > 0.f ? x : 0.2f * x;
                float w = __expf(x);
                s += w;
#pragma unroll
                for (int i = 0; i < 8; ++i) a[i] += w * fl[i];
            }
        }
    }
    // combine halves (both halves end with full sums)
#pragma unroll
    for (int i = 0; i < 8; ++i) a[i] += __shfl_xor(a[i], 32);
    s += __shfl_xor(s, 32);
    float inv = deg_t > 0 ? 1.0f / s : 0.f;

    // write: lane stores 4 floats at float4-index l*2+half of the row
    int fi = l * 2 + half;
    float4 bb = reinterpret_cast<const float4*>(bias)[fi];
    int base = half * 4;
    float4 o;
    o.x = a[base + 0] * inv + bb.x;
    o.y = a[base + 1] * inv + bb.y;
    o.z = a[base + 2] * inv + bb.z;
    o.w = a[base + 3] * inv + bb.w;
    reinterpret_cast<float4*>(out)[(size_t)v * 64 + fi] = o;
}

// ------------------------------------------------------- launch (3 dispatches)
extern "C" void kernel_launch(void* const* d_in, const int* in_sizes, int n_in,
                              void* d_out, int out_size, void* d_ws, size_t ws_size,
                              hipStream_t stream) {
    const float* feat   = (const float*)d_in[0];
    const float* W      = (const float*)d_in[1];
    const float* attn_l = (const float*)d_in[2];
    const float* attn_r = (const float*)d_in[3];
    const float* bias   = (const float*)d_in[4];
    const int* src = (const int*)d_in[5];
    const int* dst = (const int*)d_in[6];
    float* out = (float*)d_out;

    char* ws = (char*)d_ws;
    // workspace layout (16B aligned) -- offsets kept from r7 (el/er regions
    // now unused; zero-risk layout diff)
    unsigned short* Wt     = (unsigned short*)(ws + 0);          //    131,072
    unsigned short* ft     = (unsigned short*)(ws + 147456);     // 25,600,000
    int* cursor            = (int*)(ws + 28947456);              //    200,704
    int* spill_n           = (int*)(ws + 29148160);              //         64
    int2* spill            = (int2*)(ws + 29148224);             //     65,536
    unsigned short* inedge = (unsigned short*)(ws + 29213760);   // stride*2*NPAD

    // bucket stride: multiple of 8 (16B-aligned rows for uint4 index loads),
    // cap 64. Poisson(16) degrees (max ~38 this dataset); spill list keeps
    // any overflow exact regardless.
    size_t avail = ws_size > 29213760ull ? ws_size - 29213760ull : 0;
    int stride = (int)(avail / (2ull * NPAD));
    stride &= ~7;
    if (stride > 64) stride = 64;
    if (stride < 8) stride = 8;

    prep_w<<<212, 256, 0, stream>>>(W, Wt, cursor, spill_n);
    gemm_bucket<<<GEMM_BLOCKS + BUCKET_BLOCKS, 512, 0, stream>>>(
        feat, Wt, ft, src, dst, cursor, inedge, spill_n, spill, stride);
    aggregate<<<12500, 256, 0, stream>>>(ft, attn_l, attn_r, cursor, inedge,
                                         spill_n, spill, bias, out, stride);
}